// Round 2
// baseline (711.451 us; speedup 1.0000x reference)
//
#include <hip/hip_runtime.h>

#define N_NODES 8192
#define N_EDGES 4096
#define F_INS   256
#define HEADS   8
#define DOUT    64
#define HDIM    512   // HEADS*DOUT
#define CCOMB   1024  // 2*HDIM (both batches as columns)
#define BATCH   2

typedef __bf16 bf16x8 __attribute__((ext_vector_type(8)));
typedef __bf16 bf16x4 __attribute__((ext_vector_type(4)));
typedef float  f32x4  __attribute__((ext_vector_type(4)));

// async 16B global->LDS (wave-uniform LDS base + lane*16)
__device__ __forceinline__ void gld_lds16(const __bf16* g, __bf16* l) {
    __builtin_amdgcn_global_load_lds(
        (const __attribute__((address_space(1))) void*)g,
        (__attribute__((address_space(3))) void*)l, 16, 0, 0);
}

// ---------- H (fp32 N x E) -> Hb (bf16 N x E) and HbT (bf16 E x N) ----------
__launch_bounds__(256)
__global__ void convert_H_kernel(const float* __restrict__ H,
                                 __bf16* __restrict__ Hb,
                                 __bf16* __restrict__ HbT) {
    __shared__ __bf16 tile[32][33];
    int e0 = blockIdx.x * 32, n0 = blockIdx.y * 32;
    int t = threadIdx.x;
    int c = t & 31, r0 = t >> 5;
#pragma unroll
    for (int p = 0; p < 4; ++p) {
        int r = p * 8 + r0;
        float v = H[(size_t)(n0 + r) * N_EDGES + e0 + c];
        __bf16 bv = (__bf16)v;
        Hb[(size_t)(n0 + r) * N_EDGES + e0 + c] = bv;
        tile[r][c] = bv;
    }
    __syncthreads();
#pragma unroll
    for (int p = 0; p < 4; ++p) {
        int er = p * 8 + r0;
        HbT[(size_t)(e0 + er) * N_NODES + n0 + c] = tile[c][er];
    }
}

// ---------- x fp32 -> bf16 (vectorized) ----------
__launch_bounds__(256)
__global__ void cvt_x_kernel(const float* __restrict__ src, __bf16* __restrict__ dst, int n4) {
    int i = blockIdx.x * 256 + threadIdx.x;
    if (i >= n4) return;
    float4 v = ((const float4*)src)[i];
    bf16x4 o;
    o.x = (__bf16)v.x; o.y = (__bf16)v.y; o.z = (__bf16)v.z; o.w = (__bf16)v.w;
    ((bf16x4*)dst)[i] = o;
}

// ---------- W (fp32 F_INS x HDIM) -> WbT (bf16 HDIM x F_INS) ----------
__launch_bounds__(256)
__global__ void wbt_kernel(const float* __restrict__ W, __bf16* __restrict__ WbT) {
    int i = blockIdx.x * 256 + threadIdx.x;  // 512*256 = 131072
    int c = i >> 8, f = i & 255;
    WbT[i] = (__bf16)W[(size_t)f * HDIM + c];
}

// ---------- Wa[f][h] = sum_d W[f][h*64+d] * a[d]  (fp32, exact path for av) ----------
__launch_bounds__(256)
__global__ void wa_kernel(const float* __restrict__ W, const float* __restrict__ a,
                          float* __restrict__ Wa) {
    int i = blockIdx.x * 256 + threadIdx.x;  // 2048
    if (i >= F_INS * HEADS) return;
    int f = i >> 3, h = i & 7;
    float s = 0.f;
#pragma unroll 8
    for (int d = 0; d < DOUT; ++d) s += W[(size_t)f * HDIM + h * DOUT + d] * a[d];
    Wa[i] = s;
}

// ---------- av[b,n,h] = leaky_relu( x[b,n,:] . Wa[:,h] )  fully fp32 ----------
__launch_bounds__(256)
__global__ void av_kernel(const float* __restrict__ x, const float* __restrict__ Wa,
                          float* __restrict__ av) {
    __shared__ float lx[32][257];
    __shared__ float lwa[F_INS * HEADS];
    int t = threadIdx.x;
    size_t row0 = (size_t)blockIdx.x * 32;  // rows = b*8192+n, 16384 total
    for (int p = t; p < F_INS * HEADS; p += 256) lwa[p] = Wa[p];
#pragma unroll
    for (int p = 0; p < 32; ++p) lx[p][t] = x[(row0 + p) * F_INS + t];
    __syncthreads();
    int r = t >> 3, h = t & 7;
    float acc = 0.f;
#pragma unroll 8
    for (int f = 0; f < F_INS; ++f) acc += lx[r][f] * lwa[f * 8 + h];
    av[(row0 + r) * 8 + h] = acc > 0.f ? acc : 0.2f * acc;
}

// ---------- logits[bh][e] += sum over n-chunk of H[n,e]*av[b,n,h]  (fp32) ----------
__launch_bounds__(256)
__global__ void logits_kernel(const float* __restrict__ H, const float* __restrict__ av,
                              float* __restrict__ logits) {
    __shared__ float lav[512 * 16];
    int t = threadIdx.x;
    int e = blockIdx.x * 256 + t;
    int n0 = blockIdx.y * 512;
    for (int p = t; p < 8192; p += 256) {
        int b = p >> 12, rem = p & 4095, i = rem >> 3, h = rem & 7;
        lav[i * 16 + b * 8 + h] = av[(size_t)b * (N_NODES * 8) + (size_t)(n0 + i) * 8 + h];
    }
    __syncthreads();
    float acc[16];
#pragma unroll
    for (int bh = 0; bh < 16; ++bh) acc[bh] = 0.f;
    for (int i = 0; i < 512; ++i) {
        float hv = H[(size_t)(n0 + i) * N_EDGES + e];
#pragma unroll
        for (int bh = 0; bh < 16; ++bh) acc[bh] += hv * lav[i * 16 + bh];
    }
#pragma unroll
    for (int bh = 0; bh < 16; ++bh)
        atomicAdd(&logits[(size_t)bh * N_EDGES + e], acc[bh]);
}

// ---------- softmax over e for each of 16 (b,h) rows, in place ----------
__launch_bounds__(256)
__global__ void softmax_kernel(float* __restrict__ logits) {
    __shared__ float red[4];
    __shared__ float reds[4];
    int t = threadIdx.x;
    float* row = logits + (size_t)blockIdx.x * N_EDGES;
    float mx = -1e30f;
    for (int i = t; i < N_EDGES; i += 256) mx = fmaxf(mx, row[i]);
#pragma unroll
    for (int o = 32; o > 0; o >>= 1) mx = fmaxf(mx, __shfl_xor(mx, o, 64));
    if ((t & 63) == 0) red[t >> 6] = mx;
    __syncthreads();
    mx = fmaxf(fmaxf(red[0], red[1]), fmaxf(red[2], red[3]));
    float s = 0.f;
    for (int i = t; i < N_EDGES; i += 256) {
        float v = expf(row[i] - mx);
        row[i] = v;
        s += v;
    }
#pragma unroll
    for (int o = 32; o > 0; o >>= 1) s += __shfl_xor(s, o, 64);
    if ((t & 63) == 0) reds[t >> 6] = s;
    __syncthreads();
    float inv = 1.0f / (reds[0] + reds[1] + reds[2] + reds[3]);
    for (int i = t; i < N_EDGES; i += 256) row[i] *= inv;
}

// ---------- 128x128 bf16 MFMA GEMM, fragment-major LDS, global_load_lds staging ----
// C[m][n] = sum_k A[m][k] * BT[n][k], K split over blockIdx.z (a_bz/bt_bz = elem
// offsets per z on A/BT).
// MODE 0: store bf16 to outB[gm*ldo+gc] (+out_bz per z)           (WhT)
// MODE 1: fp32 atomicAdd into outF[gm*ldo+gc]                     (acc1 for mwT)
// MODE 2: fp32 atomicAdd into out[(gc>>9)][gm][gc&511]            (final out)
template <int MODE>
__launch_bounds__(256, 4)
__global__ void gemm_bt(const __bf16* __restrict__ A, const __bf16* __restrict__ BT,
                        int lda, int ldbt, int K,
                        size_t a_bz, size_t bt_bz, size_t out_bz,
                        __bf16* __restrict__ outB, int ldo,
                        float* __restrict__ outF) {
    // fragment-major: block bid = mblk*2+kblk (mblk<8, kblk<2), 1024B = lane*16B
    __shared__ __bf16 AsF[8192];
    __shared__ __bf16 BsF[8192];
    int t = threadIdx.x;
    int bz = blockIdx.z;
    A  += (size_t)bz * a_bz;
    BT += (size_t)bz * bt_bz;
    if (MODE == 0) outB += (size_t)bz * out_bz;
    size_t m0 = (size_t)blockIdx.y * 128;
    size_t n0 = (size_t)blockIdx.x * 128;

    int lane = t & 63, wv = t >> 6;
    int ln = lane & 15, lk = lane >> 4;  // fragment row / k-quad

    const __bf16* pA[4]; const __bf16* pB[4];
    __bf16* lA[4]; __bf16* lB[4];
#pragma unroll
    for (int p = 0; p < 4; ++p) {
        int bid = wv * 4 + p;
        int mb = bid >> 1, kb = bid & 1;
        pA[p] = A + (m0 + mb * 16 + ln) * (size_t)lda + kb * 32 + lk * 8;
        pB[p] = BT + (n0 + mb * 16 + ln) * (size_t)ldbt + kb * 32 + lk * 8;
        lA[p] = &AsF[bid * 512];
        lB[p] = &BsF[bid * 512];
    }

    int wm16 = (wv & 1) * 4, wn16 = (wv >> 1) * 4;
    f32x4 acc[4][4] = {};

    for (int k0 = 0; k0 < K; k0 += 64) {
        __syncthreads();
#pragma unroll
        for (int p = 0; p < 4; ++p) gld_lds16(pA[p] + k0, lA[p]);
#pragma unroll
        for (int p = 0; p < 4; ++p) gld_lds16(pB[p] + k0, lB[p]);
        __syncthreads();
#pragma unroll
        for (int ksb = 0; ksb < 2; ++ksb) {
            bf16x8 af[4], bfr[4];
#pragma unroll
            for (int i = 0; i < 4; ++i)
                af[i] = *(const bf16x8*)&AsF[((wm16 + i) * 2 + ksb) * 512 + lane * 8];
#pragma unroll
            for (int j = 0; j < 4; ++j)
                bfr[j] = *(const bf16x8*)&BsF[((wn16 + j) * 2 + ksb) * 512 + lane * 8];
#pragma unroll
            for (int i = 0; i < 4; ++i)
#pragma unroll
                for (int j = 0; j < 4; ++j)
                    acc[i][j] = __builtin_amdgcn_mfma_f32_16x16x32_bf16(
                        af[i], bfr[j], acc[i][j], 0, 0, 0);
        }
    }

    int wm = (wv & 1) * 64, wn = (wv >> 1) * 64;
#pragma unroll
    for (int i = 0; i < 4; ++i)
#pragma unroll
        for (int j = 0; j < 4; ++j)
#pragma unroll
            for (int rg = 0; rg < 4; ++rg) {
                int gm = (int)m0 + wm + i * 16 + lk * 4 + rg;
                int gc = (int)n0 + wn + j * 16 + ln;
                float v = acc[i][j][rg];
                if (MODE == 0) {
                    outB[(size_t)gm * ldo + gc] = (__bf16)v;
                } else if (MODE == 1) {
                    atomicAdd(&outF[(size_t)gm * ldo + gc], v);
                } else {
                    atomicAdd(&outF[(size_t)(gc >> 9) * ((size_t)N_NODES * HDIM) +
                                    (size_t)gm * HDIM + (gc & 511)], v);
                }
            }
}

// ---------- mwT = bf16(acc1 * ae) ----------
__launch_bounds__(256)
__global__ void scale1_kernel(const float* __restrict__ acc1, const float* __restrict__ ae,
                              __bf16* __restrict__ mwT) {
    int i = blockIdx.x * 256 + threadIdx.x;  // float4 index, 1M total
    size_t base = (size_t)i * 4;
    int c = (int)(base >> 12);
    int e = (int)(base & 4095);
    float4 s = ((const float4*)acc1)[i];
    float4 a4 = *(const float4*)(ae + ((size_t)(c >> 6) << 12) + e);
    bf16x4 o;
    o.x = (__bf16)(s.x * a4.x);
    o.y = (__bf16)(s.y * a4.y);
    o.z = (__bf16)(s.z * a4.z);
    o.w = (__bf16)(s.w * a4.w);
    ((bf16x4*)mwT)[i] = o;
}

extern "C" void kernel_launch(void* const* d_in, const int* in_sizes, int n_in,
                              void* d_out, int out_size, void* d_ws, size_t ws_size,
                              hipStream_t stream) {
    const float* x = (const float*)d_in[0];
    const float* H = (const float*)d_in[1];
    const float* W = (const float*)d_in[2];
    const float* a = (const float*)d_in[3];
    float* out = (float*)d_out;

    // workspace carve-up (~186 MB)
    char* p = (char*)d_ws;
    __bf16* Hb   = (__bf16*)p; p += (size_t)N_NODES * N_EDGES * 2;   // 67.1 MB
    __bf16* HbT  = (__bf16*)p; p += (size_t)N_EDGES * N_NODES * 2;   // 67.1 MB
    __bf16* xb   = (__bf16*)p; p += (size_t)BATCH * N_NODES * F_INS * 2; // 8.4 MB
    __bf16* WbT  = (__bf16*)p; p += (size_t)HDIM * F_INS * 2;        // 0.26 MB
    __bf16* WhbT = (__bf16*)p; p += (size_t)CCOMB * N_NODES * 2;     // 16.8 MB
    __bf16* mwT  = (__bf16*)p; p += (size_t)CCOMB * N_EDGES * 2;     // 8.4 MB
    float*  Wa   = (float*)p;  p += (size_t)F_INS * HEADS * 4;
    float*  av   = (float*)p;  p += (size_t)BATCH * N_NODES * HEADS * 4;
    float*  ae   = (float*)p;  p += (size_t)16 * N_EDGES * 4;        // logits->softmax in place
    float*  acc1 = (float*)p;  p += (size_t)CCOMB * N_EDGES * 4;     // 16.8 MB fp32 accum

    // zero-init accumulation targets (poisoned each call)
    hipMemsetAsync(ae, 0, (size_t)16 * N_EDGES * 4, stream);
    hipMemsetAsync(acc1, 0, (size_t)CCOMB * N_EDGES * 4, stream);
    hipMemsetAsync(out, 0, (size_t)BATCH * N_NODES * HDIM * 4, stream);

    convert_H_kernel<<<dim3(N_EDGES / 32, N_NODES / 32), 256, 0, stream>>>(H, Hb, HbT);
    cvt_x_kernel<<<dim3(BATCH * N_NODES * F_INS / 4 / 256), 256, 0, stream>>>(
        x, xb, BATCH * N_NODES * F_INS / 4);
    wbt_kernel<<<dim3(HDIM * F_INS / 256), 256, 0, stream>>>(W, WbT);
    wa_kernel<<<dim3(8), 256, 0, stream>>>(W, a, Wa);
    av_kernel<<<dim3(BATCH * N_NODES / 32), 256, 0, stream>>>(x, Wa, av);

    // WhbT[b*512+c][n] = sum_f WbT[c][f] * xb[b][n][f]   (K=256, no split)
    gemm_bt<0><<<dim3(64, 4, 2), 256, 0, stream>>>(
        WbT, xb, F_INS, F_INS, F_INS,
        0, (size_t)N_NODES * F_INS, (size_t)HDIM * N_NODES,
        WhbT, N_NODES, nullptr);

    logits_kernel<<<dim3(16, 16), 256, 0, stream>>>(H, av, ae);
    softmax_kernel<<<dim3(16), 256, 0, stream>>>(ae);

    // acc1[c][e] += sum_n WhbT[c][n] * HbT[e][n]   (K=8192 split 4 -> 1024 blocks)
    gemm_bt<1><<<dim3(32, 8, 4), 256, 0, stream>>>(
        WhbT, HbT, N_NODES, N_NODES, 2048,
        2048, 2048, 0,
        nullptr, N_EDGES, acc1);

    // mwT[c][e] = bf16(acc1[c][e] * ae[c>>6][e])
    scale1_kernel<<<dim3(CCOMB * N_EDGES / 4 / 256), 256, 0, stream>>>(acc1, ae, mwT);

    // out[b][n][hd] += sum_e Hb[n][e] * mwT[b*512+hd][e] (K=4096 split 2 -> 1024 blocks)
    gemm_bt<2><<<dim3(8, 64, 2), 256, 0, stream>>>(
        Hb, mwT, N_EDGES, N_EDGES, 2048,
        2048, 2048, 0,
        nullptr, 0, out);
}

// Round 3
// 567.200 us; speedup vs baseline: 1.2543x; 1.2543x over previous
//
#include <hip/hip_runtime.h>

#define N_NODES 8192
#define N_EDGES 4096
#define F_INS   256
#define HEADS   8
#define DOUT    64
#define HDIM    512   // HEADS*DOUT
#define CCOMB   1024  // 2*HDIM (both batches as columns)
#define BATCH   2

typedef __bf16 bf16x8 __attribute__((ext_vector_type(8)));
typedef __bf16 bf16x4 __attribute__((ext_vector_type(4)));
typedef float  f32x4  __attribute__((ext_vector_type(4)));

// async 16B global->LDS (wave-uniform LDS base + lane*16)
__device__ __forceinline__ void gld_lds16(const __bf16* g, __bf16* l) {
    __builtin_amdgcn_global_load_lds(
        (const __attribute__((address_space(1))) void*)g,
        (__attribute__((address_space(3))) void*)l, 16, 0, 0);
}

// ---------- fused: H fp32 -> Hb/HbT bf16  +  logits[bh][e] partial (fp32 exact) ----
// grid: (E/32, N/512). Reads H exactly once.
__launch_bounds__(256)
__global__ void convert_H_logits_kernel(const float* __restrict__ H,
                                        const float* __restrict__ av,
                                        __bf16* __restrict__ Hb,
                                        __bf16* __restrict__ HbT,
                                        float* __restrict__ logits) {
    __shared__ float lav[512 * 16];     // 32 KB
    __shared__ __bf16 tile[32][33];     // 2.1 KB
    __shared__ float red[256 * 16];     // 16 KB
    int t = threadIdx.x;
    int e0 = blockIdx.x * 32;
    int n0 = blockIdx.y * 512;
    // stage av rows [n0, n0+512), 16 bh each
    for (int p = t; p < 8192; p += 256) {
        int b = p >> 12, rem = p & 4095, i = rem >> 3, h = rem & 7;
        lav[i * 16 + b * 8 + h] = av[(size_t)b * (N_NODES * 8) + (size_t)(n0 + i) * 8 + h];
    }
    __syncthreads();
    int c = t & 31, r0 = t >> 5;
    float acc[16];
#pragma unroll
    for (int q = 0; q < 16; ++q) acc[q] = 0.f;
    for (int sub = 0; sub < 16; ++sub) {
        int nb = n0 + sub * 32;
#pragma unroll
        for (int p = 0; p < 4; ++p) {
            int r = p * 8 + r0;
            float v = H[(size_t)(nb + r) * N_EDGES + e0 + c];
            __bf16 bv = (__bf16)v;
            Hb[(size_t)(nb + r) * N_EDGES + e0 + c] = bv;
            tile[r][c] = bv;
            const float* lr = &lav[(sub * 32 + r) * 16];
#pragma unroll
            for (int q = 0; q < 16; ++q) acc[q] += v * lr[q];
        }
        __syncthreads();
#pragma unroll
        for (int p = 0; p < 4; ++p) {
            int er = p * 8 + r0;
            HbT[(size_t)(e0 + er) * N_NODES + nb + c] = tile[c][er];
        }
        __syncthreads();
    }
#pragma unroll
    for (int q = 0; q < 16; ++q) red[t * 16 + q] = acc[q];
    __syncthreads();
    for (int o = t; o < 512; o += 256) {
        int e = o & 31, q = o >> 5;
        float s = 0.f;
#pragma unroll
        for (int r8 = 0; r8 < 8; ++r8) s += red[(r8 * 32 + e) * 16 + q];
        atomicAdd(&logits[(size_t)q * N_EDGES + e0 + e], s);
    }
}

// ---------- W (fp32 F_INS x HDIM) -> WbT (bf16 HDIM x F_INS) ----------
__launch_bounds__(256)
__global__ void wbt_kernel(const float* __restrict__ W, __bf16* __restrict__ WbT) {
    int i = blockIdx.x * 256 + threadIdx.x;  // 512*256 = 131072
    int c = i >> 8, f = i & 255;
    WbT[i] = (__bf16)W[(size_t)f * HDIM + c];
}

// ---------- Wa[f][h] = sum_d W[f][h*64+d] * a[d]  (fp32, exact path for av) ----------
__launch_bounds__(256)
__global__ void wa_kernel(const float* __restrict__ W, const float* __restrict__ a,
                          float* __restrict__ Wa) {
    int i = blockIdx.x * 256 + threadIdx.x;  // 2048
    if (i >= F_INS * HEADS) return;
    int f = i >> 3, h = i & 7;
    float s = 0.f;
#pragma unroll 8
    for (int d = 0; d < DOUT; ++d) s += W[(size_t)f * HDIM + h * DOUT + d] * a[d];
    Wa[i] = s;
}

// ---------- fused: av = leaky_relu(x . Wa) fp32  +  xb = bf16(x) ----------
__launch_bounds__(256)
__global__ void av_kernel(const float* __restrict__ x, const float* __restrict__ Wa,
                          float* __restrict__ av, __bf16* __restrict__ xb) {
    __shared__ float lx[32][257];
    __shared__ float lwa[F_INS * HEADS];
    int t = threadIdx.x;
    size_t row0 = (size_t)blockIdx.x * 32;  // rows = b*8192+n, 16384 total
    for (int p = t; p < F_INS * HEADS; p += 256) lwa[p] = Wa[p];
#pragma unroll
    for (int p = 0; p < 32; ++p) {
        float v = x[(row0 + p) * F_INS + t];
        lx[p][t] = v;
        xb[(row0 + p) * F_INS + t] = (__bf16)v;
    }
    __syncthreads();
    int r = t >> 3, h = t & 7;
    float acc = 0.f;
#pragma unroll 8
    for (int f = 0; f < F_INS; ++f) acc += lx[r][f] * lwa[f * 8 + h];
    av[(row0 + r) * 8 + h] = acc > 0.f ? acc : 0.2f * acc;
}

// ---------- softmax over e for each of 16 (b,h) rows, in place ----------
__launch_bounds__(256)
__global__ void softmax_kernel(float* __restrict__ logits) {
    __shared__ float red[4];
    __shared__ float reds[4];
    int t = threadIdx.x;
    float* row = logits + (size_t)blockIdx.x * N_EDGES;
    float mx = -1e30f;
    for (int i = t; i < N_EDGES; i += 256) mx = fmaxf(mx, row[i]);
#pragma unroll
    for (int o = 32; o > 0; o >>= 1) mx = fmaxf(mx, __shfl_xor(mx, o, 64));
    if ((t & 63) == 0) red[t >> 6] = mx;
    __syncthreads();
    mx = fmaxf(fmaxf(red[0], red[1]), fmaxf(red[2], red[3]));
    float s = 0.f;
    for (int i = t; i < N_EDGES; i += 256) {
        float v = expf(row[i] - mx);
        row[i] = v;
        s += v;
    }
#pragma unroll
    for (int o = 32; o > 0; o >>= 1) s += __shfl_xor(s, o, 64);
    if ((t & 63) == 0) reds[t >> 6] = s;
    __syncthreads();
    float inv = 1.0f / (reds[0] + reds[1] + reds[2] + reds[3]);
    for (int i = t; i < N_EDGES; i += 256) row[i] *= inv;
}

// ---------- 128x128 bf16 MFMA GEMM, fragment-major LDS, global_load_lds staging ----
// C[m][n] = sum_k A[m][k] * BT[n][k], optional K split over blockIdx.z
// (a_bz/bt_bz = element offsets per z; out_z = element offset per z on output).
// MODE 0: store bf16 to outB[gm*ldo+gc] (+out_z per z)      (WhT)
// MODE 1: plain fp32 store outF[gm*ldo+gc] (+out_z per z)   (acc1 slabs for mwT)
// MODE 2: plain fp32 store out[(gc>>9)][gm][gc&511]         (final out)
template <int MODE>
__launch_bounds__(256, 4)
__global__ void gemm_bt(const __bf16* __restrict__ A, const __bf16* __restrict__ BT,
                        int lda, int ldbt, int K,
                        size_t a_bz, size_t bt_bz, size_t out_z,
                        __bf16* __restrict__ outB, int ldo,
                        float* __restrict__ outF) {
    // fragment-major: block bid = mblk*2+kblk (mblk<8, kblk<2), 1024B = lane*16B
    __shared__ __bf16 AsF[8192];
    __shared__ __bf16 BsF[8192];
    int t = threadIdx.x;
    int bz = blockIdx.z;
    A  += (size_t)bz * a_bz;
    BT += (size_t)bz * bt_bz;
    if (MODE == 0) outB += (size_t)bz * out_z;
    if (MODE == 1) outF += (size_t)bz * out_z;
    size_t m0 = (size_t)blockIdx.y * 128;
    size_t n0 = (size_t)blockIdx.x * 128;

    int lane = t & 63, wv = t >> 6;
    int ln = lane & 15, lk = lane >> 4;  // fragment row / k-quad

    const __bf16* pA[4]; const __bf16* pB[4];
    __bf16* lA[4]; __bf16* lB[4];
#pragma unroll
    for (int p = 0; p < 4; ++p) {
        int bid = wv * 4 + p;
        int mb = bid >> 1, kb = bid & 1;
        pA[p] = A + (m0 + mb * 16 + ln) * (size_t)lda + kb * 32 + lk * 8;
        pB[p] = BT + (n0 + mb * 16 + ln) * (size_t)ldbt + kb * 32 + lk * 8;
        lA[p] = &AsF[bid * 512];
        lB[p] = &BsF[bid * 512];
    }

    int wm16 = (wv & 1) * 4, wn16 = (wv >> 1) * 4;
    f32x4 acc[4][4] = {};

    for (int k0 = 0; k0 < K; k0 += 64) {
        __syncthreads();
#pragma unroll
        for (int p = 0; p < 4; ++p) gld_lds16(pA[p] + k0, lA[p]);
#pragma unroll
        for (int p = 0; p < 4; ++p) gld_lds16(pB[p] + k0, lB[p]);
        __syncthreads();
#pragma unroll
        for (int ksb = 0; ksb < 2; ++ksb) {
            bf16x8 af[4], bfr[4];
#pragma unroll
            for (int i = 0; i < 4; ++i)
                af[i] = *(const bf16x8*)&AsF[((wm16 + i) * 2 + ksb) * 512 + lane * 8];
#pragma unroll
            for (int j = 0; j < 4; ++j)
                bfr[j] = *(const bf16x8*)&BsF[((wn16 + j) * 2 + ksb) * 512 + lane * 8];
#pragma unroll
            for (int i = 0; i < 4; ++i)
#pragma unroll
                for (int j = 0; j < 4; ++j)
                    acc[i][j] = __builtin_amdgcn_mfma_f32_16x16x32_bf16(
                        af[i], bfr[j], acc[i][j], 0, 0, 0);
        }
    }

    int wm = (wv & 1) * 64, wn = (wv >> 1) * 64;
#pragma unroll
    for (int i = 0; i < 4; ++i)
#pragma unroll
        for (int j = 0; j < 4; ++j)
#pragma unroll
            for (int rg = 0; rg < 4; ++rg) {
                int gm = (int)m0 + wm + i * 16 + lk * 4 + rg;
                int gc = (int)n0 + wn + j * 16 + ln;
                float v = acc[i][j][rg];
                if (MODE == 0) {
                    outB[(size_t)gm * ldo + gc] = (__bf16)v;
                } else if (MODE == 1) {
                    outF[(size_t)gm * ldo + gc] = v;
                } else {
                    outF[(size_t)(gc >> 9) * ((size_t)N_NODES * HDIM) +
                         (size_t)gm * HDIM + (gc & 511)] = v;
                }
            }
}

// ---------- mwT = bf16( (slab0+slab1+slab2+slab3) * ae ) ----------
__launch_bounds__(256)
__global__ void scale1_kernel(const float* __restrict__ acc1, const float* __restrict__ ae,
                              __bf16* __restrict__ mwT) {
    int i = blockIdx.x * 256 + threadIdx.x;  // float4 index, 1M total
    size_t base = (size_t)i * 4;
    int c = (int)(base >> 12);
    int e = (int)(base & 4095);
    const size_t slab = (size_t)CCOMB * N_EDGES / 4;  // float4 units
    float4 s0 = ((const float4*)acc1)[i];
    float4 s1 = ((const float4*)acc1)[i + slab];
    float4 s2 = ((const float4*)acc1)[i + 2 * slab];
    float4 s3 = ((const float4*)acc1)[i + 3 * slab];
    float4 a4 = *(const float4*)(ae + ((size_t)(c >> 6) << 12) + e);
    bf16x4 o;
    o.x = (__bf16)((s0.x + s1.x + s2.x + s3.x) * a4.x);
    o.y = (__bf16)((s0.y + s1.y + s2.y + s3.y) * a4.y);
    o.z = (__bf16)((s0.z + s1.z + s2.z + s3.z) * a4.z);
    o.w = (__bf16)((s0.w + s1.w + s2.w + s3.w) * a4.w);
    ((bf16x4*)mwT)[i] = o;
}

extern "C" void kernel_launch(void* const* d_in, const int* in_sizes, int n_in,
                              void* d_out, int out_size, void* d_ws, size_t ws_size,
                              hipStream_t stream) {
    const float* x = (const float*)d_in[0];
    const float* H = (const float*)d_in[1];
    const float* W = (const float*)d_in[2];
    const float* a = (const float*)d_in[3];
    float* out = (float*)d_out;

    // workspace carve-up (~235 MB)
    char* p = (char*)d_ws;
    __bf16* Hb   = (__bf16*)p; p += (size_t)N_NODES * N_EDGES * 2;   // 67.1 MB
    __bf16* HbT  = (__bf16*)p; p += (size_t)N_EDGES * N_NODES * 2;   // 67.1 MB
    __bf16* xb   = (__bf16*)p; p += (size_t)BATCH * N_NODES * F_INS * 2; // 8.4 MB
    __bf16* WbT  = (__bf16*)p; p += (size_t)HDIM * F_INS * 2;        // 0.26 MB
    __bf16* WhbT = (__bf16*)p; p += (size_t)CCOMB * N_NODES * 2;     // 16.8 MB
    __bf16* mwT  = (__bf16*)p; p += (size_t)CCOMB * N_EDGES * 2;     // 8.4 MB
    float*  Wa   = (float*)p;  p += (size_t)F_INS * HEADS * 4;
    float*  av   = (float*)p;  p += (size_t)BATCH * N_NODES * HEADS * 4;
    float*  ae   = (float*)p;  p += (size_t)16 * N_EDGES * 4;        // logits->softmax in place
    float*  acc1 = (float*)p;  p += (size_t)4 * CCOMB * N_EDGES * 4; // 67.1 MB: 4 fp32 slabs

    // only the logits accumulator needs zeroing (atomic target)
    hipMemsetAsync(ae, 0, (size_t)16 * N_EDGES * 4, stream);

    wbt_kernel<<<dim3(HDIM * F_INS / 256), 256, 0, stream>>>(W, WbT);
    wa_kernel<<<dim3(8), 256, 0, stream>>>(W, a, Wa);
    av_kernel<<<dim3(BATCH * N_NODES / 32), 256, 0, stream>>>(x, Wa, av, xb);
    convert_H_logits_kernel<<<dim3(N_EDGES / 32, N_NODES / 512), 256, 0, stream>>>(
        H, av, Hb, HbT, ae);
    softmax_kernel<<<dim3(16), 256, 0, stream>>>(ae);

    // WhbT[b*512+c][n] = sum_f WbT[c][f] * xb[b][n][f]   (K=256, no split)
    gemm_bt<0><<<dim3(64, 4, 2), 256, 0, stream>>>(
        WbT, xb, F_INS, F_INS, F_INS,
        0, (size_t)N_NODES * F_INS, (size_t)HDIM * N_NODES,
        WhbT, N_NODES, nullptr);

    // acc1 slab z: [c][e] = sum over n-slab of WhbT[c][n]*HbT[e][n]
    // (K=8192 -> 4 slabs of 2048; 1024 blocks = 4/CU; plain stores, no atomics)
    gemm_bt<1><<<dim3(32, 8, 4), 256, 0, stream>>>(
        WhbT, HbT, N_NODES, N_NODES, 2048,
        2048, 2048, (size_t)CCOMB * N_EDGES,
        nullptr, N_EDGES, acc1);

    // mwT[c][e] = bf16( (sum of 4 slabs) * ae[c>>6][e] )
    scale1_kernel<<<dim3(CCOMB * N_EDGES / 4 / 256), 256, 0, stream>>>(acc1, ae, mwT);

    // out[b][n][hd] = sum_e Hb[n][e] * mwT[b*512+hd][e]
    // (K=4096 unsplit; 512 blocks = 2/CU; direct fp32 stores)
    gemm_bt<2><<<dim3(8, 64, 1), 256, 0, stream>>>(
        Hb, mwT, N_EDGES, N_EDGES, N_EDGES,
        0, 0, 0,
        nullptr, 0, out);
}